// Round 11
// baseline (134.300 us; speedup 1.0000x reference)
//
#include <hip/hip_runtime.h>
#include <math.h>

// ProxyNCA loss, MFMA version — round 11.
// logit_ic = 18 * xhat_i . phat_c ;  nll_i = log(sum_c exp(logit_ic)) - logit_{i,T_i}
// Both operands prescaled by sqrt(18*log2(e)) = 5.0959308 into bf16; the
// 16x16x32 bf16 MFMA accumulator holds log2(e)*logit, so exp = v_exp_f32.
//
// Round 11 vs round 10: ONE variable — row-split the grid x4.
// R9/R10 accounting: combined issue demand ~30us vs 65us duration; per m114
// MFMA/VALU overlap across DIFFERENT waves, so the floor needs wave supply.
// Grid was 512 = 2 blocks/CU (the real occupancy cap; VGPR 72 allows ~3
// blocks resident). Now each block sweeps 1024 rows (4 iters), grid = 2048.
// Cost: pb-build redundancy x4 (~2.5us aggregate) + P re-reads (L3-cached).
// Hot loop, registers, epilogue: identical to R10.
// Spill ledger (R2/R7/R8): only (512,2) never spilled. Keep (512,2).

#define NROWS 4096
#define NCLS  65536
#define DIM   64
#define CBLK  128                 // classes per block (register-resident P frags)
#define NBLK  (NCLS / CBLK)       // 512 class-blocks
#define RSPLIT 4                  // row quarters -> grid 2048
#define NCH   (CBLK / 16)         // 8 MFMA chunks of 16 classes

typedef __attribute__((ext_vector_type(8))) short short8;
typedef __attribute__((ext_vector_type(4))) float f32x4;

#define PRESCALE 5.0959308f       // sqrt(18 * log2(e))

__device__ __forceinline__ short bf16rne(float f) {
    union { float f; unsigned u; } v; v.f = f;
    unsigned r = (v.u + 0x7fffu + ((v.u >> 16) & 1u)) >> 16;
    return (short)r;
}

// ---- per-row prep: Xb = bf16(PRESCALE * xhat), st[r] = exact f32 target logit
__global__ void k_prep(const float* __restrict__ X, const float* __restrict__ P,
                       const int* __restrict__ T,
                       unsigned short* __restrict__ Xb, float* __restrict__ st) {
    int row  = blockIdx.x * 4 + (threadIdx.x >> 6);
    int lane = threadIdx.x & 63;
    int tc   = T[row];
    float xv = X[row * DIM + lane];
    float pv = P[tc  * DIM + lane];
    float x2 = xv * xv, p2 = pv * pv, xp = xv * pv;
    #pragma unroll
    for (int off = 32; off > 0; off >>= 1) {
        x2 += __shfl_xor(x2, off);
        p2 += __shfl_xor(p2, off);
        xp += __shfl_xor(xp, off);
    }
    float rx = rsqrtf(fmaxf(x2, 1e-24f));
    Xb[row * DIM + lane] = (unsigned short)bf16rne(xv * (PRESCALE * rx));
    if (lane == 0)
        st[row] = 18.0f * xp * rx * rsqrtf(fmaxf(p2, 1e-24f));
}

// ---- main: block (b, h): classes [b*128,+128) x rows [h*1024,+1024) ------
// 8 waves; wave w, iter it handles row-tiles h*64 + 16*it + w and +8.
// P frags normalized/converted once into 64 regs per wave.
// mfma(P_frag, X_frag): C col = lane&15 = x-row, regs = 4 classes.
// Epilogue per tile: one shfl_xor(32); lanes 0..31 store 2 partials/row.
__global__ __launch_bounds__(512, 2)
void k_main(const float* __restrict__ prox, const unsigned short* __restrict__ Xb,
            float* __restrict__ psum) {
    int t = threadIdx.x;
    int w = t >> 6;
    int l = t & 63;
    int bx = blockIdx.x;
    int b  = bx & (NBLK - 1);     // class block
    int h  = bx >> 9;             // row quarter
    int cb = b * CBLK;
    int lm = l & 15;              // class-in-chunk (A row) / x-row (B col)
    int lk = l >> 4;              // k-group

    // ---- one-time: load 128 classes of P (f32), normalize, convert to frags
    short8 pb[NCH][2];
    #pragma unroll
    for (int ch = 0; ch < NCH; ++ch) {
        int cls = cb + ch * 16 + lm;
        const float4* pr = reinterpret_cast<const float4*>(prox + cls * DIM + lk * 8);
        float4 a0 = pr[0], a1 = pr[1];          // k = lk*8 .. +7
        const float4* pr2 = reinterpret_cast<const float4*>(prox + cls * DIM + 32 + lk * 8);
        float4 b0 = pr2[0], b1 = pr2[1];        // k = 32 + lk*8 .. +7
        float sq = a0.x*a0.x + a0.y*a0.y + a0.z*a0.z + a0.w*a0.w
                 + a1.x*a1.x + a1.y*a1.y + a1.z*a1.z + a1.w*a1.w
                 + b0.x*b0.x + b0.y*b0.y + b0.z*b0.z + b0.w*b0.w
                 + b1.x*b1.x + b1.y*b1.y + b1.z*b1.z + b1.w*b1.w;
        sq += __shfl_xor(sq, 16);
        sq += __shfl_xor(sq, 32);
        float sc = PRESCALE * rsqrtf(fmaxf(sq, 1e-24f));
        short8 f0, f1;
        f0[0]=bf16rne(a0.x*sc); f0[1]=bf16rne(a0.y*sc); f0[2]=bf16rne(a0.z*sc); f0[3]=bf16rne(a0.w*sc);
        f0[4]=bf16rne(a1.x*sc); f0[5]=bf16rne(a1.y*sc); f0[6]=bf16rne(a1.z*sc); f0[7]=bf16rne(a1.w*sc);
        f1[0]=bf16rne(b0.x*sc); f1[1]=bf16rne(b0.y*sc); f1[2]=bf16rne(b0.z*sc); f1[3]=bf16rne(b0.w*sc);
        f1[4]=bf16rne(b1.x*sc); f1[5]=bf16rne(b1.y*sc); f1[6]=bf16rne(b1.z*sc); f1[7]=bf16rne(b1.w*sc);
        pb[ch][0] = f0;
        pb[ch][1] = f1;
    }

    const f32x4 zero = {0.0f, 0.0f, 0.0f, 0.0f};

    // ---- row sweep: 4 iterations x 2 independent tiles (A and A+128 rows)
    const short8* xpA = reinterpret_cast<const short8*>(
        Xb + (h * 1024 + w * 16 + lm) * DIM + lk * 8);
    // psum layout: [block][row][2] f32; lanes l<32 store part lk.
    float* prow = psum + ((size_t)b * NROWS + h * 1024 + w * 16 + lm) * 2 + lk;

    #pragma unroll 1
    for (int it = 0; it < 4; ++it) {
        short8 xA0 = xpA[0];
        short8 xA1 = xpA[4];          // +32 shorts (k 32..63)
        short8 xB0 = xpA[1024];       // +8192 shorts = +128 rows
        short8 xB1 = xpA[1028];

        float eA0 = 0.f, eA1 = 0.f, eA2 = 0.f, eA3 = 0.f;
        float eB0 = 0.f, eB1 = 0.f, eB2 = 0.f, eB3 = 0.f;
        #pragma unroll
        for (int ch = 0; ch < NCH; ++ch) {
            f32x4 cA = __builtin_amdgcn_mfma_f32_16x16x32_bf16(pb[ch][0], xA0, zero, 0, 0, 0);
            cA = __builtin_amdgcn_mfma_f32_16x16x32_bf16(pb[ch][1], xA1, cA, 0, 0, 0);
            f32x4 cB = __builtin_amdgcn_mfma_f32_16x16x32_bf16(pb[ch][0], xB0, zero, 0, 0, 0);
            cB = __builtin_amdgcn_mfma_f32_16x16x32_bf16(pb[ch][1], xB1, cB, 0, 0, 0);
            eA0 += __builtin_amdgcn_exp2f(cA[0]);
            eA1 += __builtin_amdgcn_exp2f(cA[1]);
            eA2 += __builtin_amdgcn_exp2f(cA[2]);
            eA3 += __builtin_amdgcn_exp2f(cA[3]);
            eB0 += __builtin_amdgcn_exp2f(cB[0]);
            eB1 += __builtin_amdgcn_exp2f(cB[1]);
            eB2 += __builtin_amdgcn_exp2f(cB[2]);
            eB3 += __builtin_amdgcn_exp2f(cB[3]);
        }
        float sA = (eA0 + eA1) + (eA2 + eA3);
        float sB = (eB0 + eB1) + (eB2 + eB3);
        sA += __shfl_xor(sA, 32);     // lane holds partial over {lk, lk^2}
        sB += __shfl_xor(sB, 32);
        if (l < 32) {
            prow[0]       = sA;       // rows h*1024 + 256*it + w*16 .. +15
            prow[128 * 2] = sB;       // +128 rows
        }

        xpA += 2048;                  // +256 rows
        prow += 256 * 2;
    }
}

// ---- per-row finish + global mean: out += sum_r (log(sum psum[.,r,.]) - st[r])/N
__global__ void k_rowred(const float* __restrict__ psum, const float* __restrict__ st,
                         float* __restrict__ out) {
    __shared__ float red[256];
    int t = threadIdx.x;
    int r = blockIdx.x * 256 + t;
    const float2* p2 = reinterpret_cast<const float2*>(psum) + r;
    float s = 0.0f;
    #pragma unroll 8
    for (int i = 0; i < NBLK; ++i) {
        float2 v = p2[i * NROWS];
        s += v.x + v.y;
    }
    red[t] = (logf(s) - st[r]) * (1.0f / (float)NROWS);
    __syncthreads();
    #pragma unroll
    for (int off = 128; off > 0; off >>= 1) {
        if (t < off) red[t] += red[t + off];
        __syncthreads();
    }
    if (t == 0) atomicAdd(out, red[0]);
}

extern "C" void kernel_launch(void* const* d_in, const int* in_sizes, int n_in,
                              void* d_out, int out_size, void* d_ws, size_t ws_size,
                              hipStream_t stream) {
    const float* X = (const float*)d_in[0];
    const float* P = (const float*)d_in[1];
    const int*   T = (const int*)  d_in[3];   // d_in[2] = indices (unused)
    float* out = (float*)d_out;

    char* ws = (char*)d_ws;
    unsigned short* Xb = (unsigned short*)ws;                 // 512 KB
    float* st   = (float*)(ws + (512 << 10));                 // 16 KB
    float* psum = (float*)(ws + (1 << 20));                   // 16 MB (512 x 4096 x 2)

    hipMemsetAsync(out, 0, sizeof(float), stream);
    k_prep  <<<NROWS / 4, 256, 0, stream>>>(X, P, T, Xb, st);
    k_main  <<<NBLK * RSPLIT, 512, 0, stream>>>(P, Xb, psum);
    k_rowred<<<NROWS / 256, 256, 0, stream>>>(psum, st, out);
}

// Round 12
// 83.272 us; speedup vs baseline: 1.6128x; 1.6128x over previous
//
#include <hip/hip_runtime.h>
#include <math.h>

// ProxyNCA loss, MFMA version — round 12.
// logit_ic = 18 * xhat_i . phat_c ;  nll_i = log(sum_c exp(logit_ic)) - logit_{i,T_i}
// Both operands prescaled by sqrt(18*log2(e)) = 5.0959308 into bf16; the
// 16x16x32 bf16 MFMA accumulator holds log2(e)*logit, so exp = v_exp_f32.
//
// Round 12 vs rounds 10/11: R11's row-split isolated the pb-build cost
// (~14us/pass: 32 dependent P-loads + norm + 32 cvt per wave) and refuted
// the TLP lever (16 waves/CU cap at >64 VGPR). So:
//  1) Pb precomputed ONCE in prep: normalized, prescaled, FRAGMENT-PACKED
//     ([chunk][half][lane][16B], R7's layout) -> k_main prologue = 16
//     coalesced 16B loads, no math. Removes ~12us from k_main.
//  2) prep_p + prep fused into one kernel (branch on blockIdx), which also
//     zeroes out[0] -> hipMemsetAsync dispatch removed. 5 dispatches -> 3.
//  Hot loop / CBLK=128 / 2-tile ILP / (512,2) / grid 512: R10 unchanged.
// Spill ledger (R2/R7/R8): only (512,2) never spilled. Keep (512,2).

#define NROWS 4096
#define NCLS  65536
#define DIM   64
#define CBLK  128                 // classes per block (register-resident P frags)
#define NBLK  (NCLS / CBLK)       // 512 class-blocks
#define NCH   (CBLK / 16)         // 8 MFMA chunks of 16 classes
#define NPB   (NCLS / 4)          // prep blocks for P (4 rows each)

typedef __attribute__((ext_vector_type(8))) short short8;
typedef __attribute__((ext_vector_type(4))) float f32x4;

#define PRESCALE 5.0959308f       // sqrt(18 * log2(e))

__device__ __forceinline__ short bf16rne(float f) {
    union { float f; unsigned u; } v; v.f = f;
    unsigned r = (v.u + 0x7fffu + ((v.u >> 16) & 1u)) >> 16;
    return (short)r;
}

// ---- fused prep: blocks [0,NPB) pack P -> Pb; blocks [NPB,..) do X/st ----
// Pb ushort index for (class row, dim d):
//   chunk=row>>4, half=d>>5, lane=(row&15)+16*((d>>3)&3), elem=d&7
//   idx = chunk*1024 + half*512 + lane*8 + elem
// In k_main, lane l's frag (ch,h) = Pb_short8[((cb8+ch)*2+h)*64 + l].
__global__ void k_prep(const float* __restrict__ X, const float* __restrict__ P,
                       const int* __restrict__ T,
                       unsigned short* __restrict__ Pb,
                       unsigned short* __restrict__ Xb, float* __restrict__ st,
                       float* __restrict__ out) {
    int bx = blockIdx.x;
    int t  = threadIdx.x;
    if (bx < NPB) {
        // ---- P branch: 4 classes per block
        int row = bx * 4 + (t >> 6);
        int d   = t & 63;
        float v  = P[row * DIM + d];
        float sq = v * v;
        #pragma unroll
        for (int off = 32; off > 0; off >>= 1) sq += __shfl_xor(sq, off);
        float sc = PRESCALE * rsqrtf(fmaxf(sq, 1e-24f));
        int idx = (row >> 4) * 1024 + (d >> 5) * 512
                + ((row & 15) + ((d >> 3) & 3) * 16) * 8 + (d & 7);
        Pb[idx] = (unsigned short)bf16rne(v * sc);
    } else {
        // ---- X branch: 4 rows per block
        if (bx == NPB && t == 0) out[0] = 0.0f;   // replaces hipMemsetAsync
        int row  = (bx - NPB) * 4 + (t >> 6);
        int lane = t & 63;
        int tc   = T[row];
        float xv = X[row * DIM + lane];
        float pv = P[tc  * DIM + lane];
        float x2 = xv * xv, p2 = pv * pv, xp = xv * pv;
        #pragma unroll
        for (int off = 32; off > 0; off >>= 1) {
            x2 += __shfl_xor(x2, off);
            p2 += __shfl_xor(p2, off);
            xp += __shfl_xor(xp, off);
        }
        float rx = rsqrtf(fmaxf(x2, 1e-24f));
        Xb[row * DIM + lane] = (unsigned short)bf16rne(xv * (PRESCALE * rx));
        if (lane == 0)
            st[row] = 18.0f * xp * rx * rsqrtf(fmaxf(p2, 1e-24f));
    }
}

// ---- main: block b owns classes [b*128,(b+1)*128); sweeps all 4096 rows ----
// 8 waves; wave w, iter it handles row-tiles (w+16it) and (w+16it+8).
// pb frags loaded pre-packed from Pb (16 coalesced 16B loads, no math).
// mfma(P_frag, X_frag): C col = lane&15 = x-row, regs = 4 classes.
// Epilogue per tile: one shfl_xor(32); lanes 0..31 store 2 partials/row.
__global__ __launch_bounds__(512, 2)
void k_main(const unsigned short* __restrict__ Pbu, const unsigned short* __restrict__ Xb,
            float* __restrict__ psum) {
    int t = threadIdx.x;
    int w = t >> 6;
    int l = t & 63;
    int b = blockIdx.x;
    int lm = l & 15;              // x-row within tile
    int lk = l >> 4;              // k-group

    // ---- prologue: load 8 chunks x 2 halves of packed P frags
    const short8* Pbv = reinterpret_cast<const short8*>(Pbu);
    int pbase = b * NCH * 2 * 64 + l;      // chunk stride = 2*64 short8
    short8 pb[NCH][2];
    #pragma unroll
    for (int ch = 0; ch < NCH; ++ch) {
        pb[ch][0] = Pbv[pbase + (ch * 2    ) * 64];
        pb[ch][1] = Pbv[pbase + (ch * 2 + 1) * 64];
    }

    const f32x4 zero = {0.0f, 0.0f, 0.0f, 0.0f};

    // ---- row sweep: 16 iterations x 2 independent tiles (A: w+16it, B: +8)
    const short8* xpA = reinterpret_cast<const short8*>(Xb + (w * 16 + lm) * DIM + lk * 8);
    // psum layout: [block][row][2] f32; lanes l<32 store part lk.
    float* prow = psum + ((size_t)b * NROWS + w * 16 + lm) * 2 + lk;

    #pragma unroll 1
    for (int it = 0; it < 16; ++it) {
        short8 xA0 = xpA[0];
        short8 xA1 = xpA[4];          // +32 shorts (k 32..63)
        short8 xB0 = xpA[1024];       // +8192 shorts = +128 rows
        short8 xB1 = xpA[1028];

        float eA0 = 0.f, eA1 = 0.f, eA2 = 0.f, eA3 = 0.f;
        float eB0 = 0.f, eB1 = 0.f, eB2 = 0.f, eB3 = 0.f;
        #pragma unroll
        for (int ch = 0; ch < NCH; ++ch) {
            f32x4 cA = __builtin_amdgcn_mfma_f32_16x16x32_bf16(pb[ch][0], xA0, zero, 0, 0, 0);
            cA = __builtin_amdgcn_mfma_f32_16x16x32_bf16(pb[ch][1], xA1, cA, 0, 0, 0);
            f32x4 cB = __builtin_amdgcn_mfma_f32_16x16x32_bf16(pb[ch][0], xB0, zero, 0, 0, 0);
            cB = __builtin_amdgcn_mfma_f32_16x16x32_bf16(pb[ch][1], xB1, cB, 0, 0, 0);
            eA0 += __builtin_amdgcn_exp2f(cA[0]);
            eA1 += __builtin_amdgcn_exp2f(cA[1]);
            eA2 += __builtin_amdgcn_exp2f(cA[2]);
            eA3 += __builtin_amdgcn_exp2f(cA[3]);
            eB0 += __builtin_amdgcn_exp2f(cB[0]);
            eB1 += __builtin_amdgcn_exp2f(cB[1]);
            eB2 += __builtin_amdgcn_exp2f(cB[2]);
            eB3 += __builtin_amdgcn_exp2f(cB[3]);
        }
        float sA = (eA0 + eA1) + (eA2 + eA3);
        float sB = (eB0 + eB1) + (eB2 + eB3);
        sA += __shfl_xor(sA, 32);     // lane holds partial over {lk, lk^2}
        sB += __shfl_xor(sB, 32);
        if (l < 32) {
            prow[0]       = sA;       // rows w*16 + 256*it .. +15, part lk
            prow[128 * 2] = sB;       // +128 rows
        }

        xpA += 2048;                  // +256 rows
        prow += 256 * 2;
    }
}

// ---- per-row finish + global mean: out += sum_r (log(sum psum[.,r,.]) - st[r])/N
__global__ void k_rowred(const float* __restrict__ psum, const float* __restrict__ st,
                         float* __restrict__ out) {
    __shared__ float red[256];
    int t = threadIdx.x;
    int r = blockIdx.x * 256 + t;
    const float2* p2 = reinterpret_cast<const float2*>(psum) + r;
    float s = 0.0f;
    #pragma unroll 8
    for (int i = 0; i < NBLK; ++i) {
        float2 v = p2[i * NROWS];
        s += v.x + v.y;
    }
    red[t] = (logf(s) - st[r]) * (1.0f / (float)NROWS);
    __syncthreads();
    #pragma unroll
    for (int off = 128; off > 0; off >>= 1) {
        if (t < off) red[t] += red[t + off];
        __syncthreads();
    }
    if (t == 0) atomicAdd(out, red[0]);
}

extern "C" void kernel_launch(void* const* d_in, const int* in_sizes, int n_in,
                              void* d_out, int out_size, void* d_ws, size_t ws_size,
                              hipStream_t stream) {
    const float* X = (const float*)d_in[0];
    const float* P = (const float*)d_in[1];
    const int*   T = (const int*)  d_in[3];   // d_in[2] = indices (unused)
    float* out = (float*)d_out;

    char* ws = (char*)d_ws;
    unsigned short* Xb = (unsigned short*)ws;                 // 512 KB
    float* st   = (float*)(ws + (512 << 10));                 // 16 KB
    unsigned short* Pb = (unsigned short*)(ws + (576 << 10)); // 8 MB (packed frags)
    float* psum = (float*)(ws + (9 << 20));                   // 16 MB (512 x 4096 x 2)

    k_prep  <<<NPB + NROWS / 4, 256, 0, stream>>>(X, P, T, Pb, Xb, st, out);
    k_main  <<<NBLK, 512, 0, stream>>>(Pb, Xb, psum);
    k_rowred<<<NROWS / 256, 256, 0, stream>>>(psum, st, out);
}

// Round 13
// 64.339 us; speedup vs baseline: 2.0874x; 1.2943x over previous
//
#include <hip/hip_runtime.h>
#include <math.h>

// ProxyNCA loss, MFMA version — round 13.
// logit_ic = 18 * xhat_i . phat_c ;  nll_i = log(sum_c exp(logit_ic)) - logit_{i,T_i}
// Both operands prescaled by sqrt(18*log2(e)) = 5.0959308 into bf16; the
// 16x16x32 bf16 MFMA accumulator holds log2(e)*logit, so exp = v_exp_f32.
//
// Round 13 vs round 12: R12's VGPR_Count=52 revealed pb lives in 64 AGPRs ->
// true per-wave allocation ~116 regs -> HW caps 16 waves/CU (m69) -> the
// occupancy ceiling all session. Changes:
//  1) P fragments moved to a 16KB LDS tile (staged once per block via
//     global_load_lds, 1 barrier, lane-contiguous 16B reads = conflict-free).
//     Frees the AGPR array -> total regs target <64 -> 32 waves/CU eligible.
//     + RSPLIT=2 (grid 1024 = 4 blocks/CU) to fill those wave slots.
//  2) k_rowred 16 -> 256 blocks (was reading 16MB on 1/16th of the chip,
//     ~20us; now 16 rows/block, 16 threads/row, LDS tree reduce).
// Hot loop math / CBLK=128 / 2-tile ILP / epilogue / (512,2): unchanged.

#define NROWS 4096
#define NCLS  65536
#define DIM   64
#define CBLK  128                 // classes per block
#define NBLK  (NCLS / CBLK)       // 512 class-blocks
#define RSPLIT 2                  // row halves -> grid 1024
#define NCH   (CBLK / 16)         // 8 MFMA chunks of 16 classes
#define NPB   (NCLS / 4)          // prep blocks for P (4 rows each)

typedef __attribute__((ext_vector_type(8))) short short8;
typedef __attribute__((ext_vector_type(4))) float f32x4;

#define PRESCALE 5.0959308f       // sqrt(18 * log2(e))

__device__ __forceinline__ short bf16rne(float f) {
    union { float f; unsigned u; } v; v.f = f;
    unsigned r = (v.u + 0x7fffu + ((v.u >> 16) & 1u)) >> 16;
    return (short)r;
}

// ---- fused prep: blocks [0,NPB) pack P -> Pb; blocks [NPB,..) do X/st ----
// Pb ushort index for (class row, dim d):
//   chunk=row>>4, half=d>>5, lane=(row&15)+16*((d>>3)&3), elem=d&7
//   idx = chunk*1024 + half*512 + lane*8 + elem
// Class-block b = chunks 8b..8b+7 = 16KB contiguous at byte offset b*16384.
__global__ void k_prep(const float* __restrict__ X, const float* __restrict__ P,
                       const int* __restrict__ T,
                       unsigned short* __restrict__ Pb,
                       unsigned short* __restrict__ Xb, float* __restrict__ st,
                       float* __restrict__ out) {
    int bx = blockIdx.x;
    int t  = threadIdx.x;
    if (bx < NPB) {
        int row = bx * 4 + (t >> 6);
        int d   = t & 63;
        float v  = P[row * DIM + d];
        float sq = v * v;
        #pragma unroll
        for (int off = 32; off > 0; off >>= 1) sq += __shfl_xor(sq, off);
        float sc = PRESCALE * rsqrtf(fmaxf(sq, 1e-24f));
        int idx = (row >> 4) * 1024 + (d >> 5) * 512
                + ((row & 15) + ((d >> 3) & 3) * 16) * 8 + (d & 7);
        Pb[idx] = (unsigned short)bf16rne(v * sc);
    } else {
        if (bx == NPB && t == 0) out[0] = 0.0f;
        int row  = (bx - NPB) * 4 + (t >> 6);
        int lane = t & 63;
        int tc   = T[row];
        float xv = X[row * DIM + lane];
        float pv = P[tc  * DIM + lane];
        float x2 = xv * xv, p2 = pv * pv, xp = xv * pv;
        #pragma unroll
        for (int off = 32; off > 0; off >>= 1) {
            x2 += __shfl_xor(x2, off);
            p2 += __shfl_xor(p2, off);
            xp += __shfl_xor(xp, off);
        }
        float rx = rsqrtf(fmaxf(x2, 1e-24f));
        Xb[row * DIM + lane] = (unsigned short)bf16rne(xv * (PRESCALE * rx));
        if (lane == 0)
            st[row] = 18.0f * xp * rx * rsqrtf(fmaxf(p2, 1e-24f));
    }
}

// ---- main: block (b,h): classes [b*128,+128) x rows [h*2048,+2048) -------
// P tile (16KB) staged once into LDS; frags re-read per chunk (ds_read_b128,
// lane-contiguous -> conflict-free). 8 waves; wave w, iter it handles
// row-tiles at rows h*2048 + 256*it + w*16 (+128 for B tile).
// mfma(P_frag, X_frag): C col = lane&15 = x-row, regs = 4 classes.
__global__ __launch_bounds__(512, 2)
void k_main(const unsigned short* __restrict__ Pbu, const unsigned short* __restrict__ Xb,
            float* __restrict__ psum) {
    __shared__ __align__(16) unsigned short plds[NCH * 2 * 512];   // 16 KB

    int t = threadIdx.x;
    int w = t >> 6;
    int l = t & 63;
    int bx = blockIdx.x;
    int b  = bx & (NBLK - 1);
    int h  = bx >> 9;
    int lm = l & 15;              // x-row within tile
    int lk = l >> 4;              // k-group

    // ---- stage P tile: 16KB linear copy (identity layout), 2 calls/wave
    {
        const char* src = reinterpret_cast<const char*>(Pbu)
                        + (size_t)b * 16384 + w * 1024 + l * 16;
        __builtin_amdgcn_global_load_lds(
            (const __attribute__((address_space(1))) unsigned int*)src,
            (__attribute__((address_space(3))) unsigned int*)((char*)plds + w * 1024),
            16, 0, 0);
        __builtin_amdgcn_global_load_lds(
            (const __attribute__((address_space(1))) unsigned int*)(src + 8192),
            (__attribute__((address_space(3))) unsigned int*)((char*)plds + 8192 + w * 1024),
            16, 0, 0);
    }
    __syncthreads();              // compiler drains vmcnt before barrier

    const f32x4 zero = {0.0f, 0.0f, 0.0f, 0.0f};

    // ---- row sweep: 8 iterations x 2 independent tiles (A and A+128 rows)
    const short8* xpA = reinterpret_cast<const short8*>(
        Xb + (h * 2048 + w * 16 + lm) * DIM + lk * 8);
    // psum layout: [block][row][2] f32; lanes l<32 store part lk.
    float* prow = psum + ((size_t)b * NROWS + h * 2048 + w * 16 + lm) * 2 + lk;
    const char* pl = (const char*)plds + l * 16;

    #pragma unroll 1
    for (int it = 0; it < 8; ++it) {
        short8 xA0 = xpA[0];
        short8 xA1 = xpA[4];          // +32 shorts (k 32..63)
        short8 xB0 = xpA[1024];       // +8192 shorts = +128 rows
        short8 xB1 = xpA[1028];

        float eA0 = 0.f, eA1 = 0.f, eA2 = 0.f, eA3 = 0.f;
        float eB0 = 0.f, eB1 = 0.f, eB2 = 0.f, eB3 = 0.f;
        #pragma unroll
        for (int ch = 0; ch < NCH; ++ch) {
            short8 p0 = *reinterpret_cast<const short8*>(pl + ch * 2048);
            short8 p1 = *reinterpret_cast<const short8*>(pl + ch * 2048 + 1024);
            f32x4 cA = __builtin_amdgcn_mfma_f32_16x16x32_bf16(p0, xA0, zero, 0, 0, 0);
            cA = __builtin_amdgcn_mfma_f32_16x16x32_bf16(p1, xA1, cA, 0, 0, 0);
            f32x4 cB = __builtin_amdgcn_mfma_f32_16x16x32_bf16(p0, xB0, zero, 0, 0, 0);
            cB = __builtin_amdgcn_mfma_f32_16x16x32_bf16(p1, xB1, cB, 0, 0, 0);
            eA0 += __builtin_amdgcn_exp2f(cA[0]);
            eA1 += __builtin_amdgcn_exp2f(cA[1]);
            eA2 += __builtin_amdgcn_exp2f(cA[2]);
            eA3 += __builtin_amdgcn_exp2f(cA[3]);
            eB0 += __builtin_amdgcn_exp2f(cB[0]);
            eB1 += __builtin_amdgcn_exp2f(cB[1]);
            eB2 += __builtin_amdgcn_exp2f(cB[2]);
            eB3 += __builtin_amdgcn_exp2f(cB[3]);
        }
        float sA = (eA0 + eA1) + (eA2 + eA3);
        float sB = (eB0 + eB1) + (eB2 + eB3);
        sA += __shfl_xor(sA, 32);     // lane holds partial over {lk, lk^2}
        sB += __shfl_xor(sB, 32);
        if (l < 32) {
            prow[0]       = sA;       // rows h*2048 + 256*it + w*16 .. +15
            prow[128 * 2] = sB;       // +128 rows
        }

        xpA += 2048;                  // +256 rows
        prow += 256 * 2;
    }
}

// ---- per-row finish + global mean, 256 blocks x 16 rows ------------------
// thread t: j = t>>4 sums i-range [j*32, +32); ri = t&15 = row in block.
__global__ void k_rowred(const float* __restrict__ psum, const float* __restrict__ st,
                         float* __restrict__ out) {
    __shared__ float red[256];
    __shared__ float rnll[16];
    int t  = threadIdx.x;
    int j  = t >> 4;
    int ri = t & 15;
    int r  = blockIdx.x * 16 + ri;
    const float2* p2 = reinterpret_cast<const float2*>(psum) + r;
    float s = 0.0f;
    #pragma unroll 4
    for (int i = j * 32; i < j * 32 + 32; ++i) {
        float2 v = p2[(size_t)i * NROWS];
        s += v.x + v.y;
    }
    red[t] = s;
    __syncthreads();
    if (t < 128) red[t] += red[t + 128];
    __syncthreads();
    if (t < 64)  red[t] += red[t + 64];
    __syncthreads();
    if (t < 32)  red[t] += red[t + 32];
    __syncthreads();
    if (t < 16) {
        float tot = red[t] + red[t + 16];
        rnll[t] = logf(tot) - st[r];
    }
    __syncthreads();
    if (t == 0) {
        float a = 0.0f;
        #pragma unroll
        for (int k = 0; k < 16; ++k) a += rnll[k];
        atomicAdd(out, a * (1.0f / (float)NROWS));
    }
}

extern "C" void kernel_launch(void* const* d_in, const int* in_sizes, int n_in,
                              void* d_out, int out_size, void* d_ws, size_t ws_size,
                              hipStream_t stream) {
    const float* X = (const float*)d_in[0];
    const float* P = (const float*)d_in[1];
    const int*   T = (const int*)  d_in[3];   // d_in[2] = indices (unused)
    float* out = (float*)d_out;

    char* ws = (char*)d_ws;
    unsigned short* Xb = (unsigned short*)ws;                 // 512 KB
    float* st   = (float*)(ws + (512 << 10));                 // 16 KB
    unsigned short* Pb = (unsigned short*)(ws + (576 << 10)); // 8 MB (packed frags)
    float* psum = (float*)(ws + (9 << 20));                   // 16 MB (512 x 4096 x 2)

    k_prep  <<<NPB + NROWS / 4, 256, 0, stream>>>(X, P, T, Pb, Xb, st, out);
    k_main  <<<NBLK * RSPLIT, 512, 0, stream>>>(Pb, Xb, psum);
    k_rowred<<<256, 256, 0, stream>>>(psum, st, out);
}